// Round 5
// baseline (284.460 us; speedup 1.0000x reference)
//
#include <hip/hip_runtime.h>
#include <hip/hip_bf16.h>

#define IN_FEATS 128
#define HD 128          // NUM_HEADS * OUT_FEATS
#define NEG_SLOPE 0.2f

static __device__ __forceinline__ unsigned short f2bf(float f) {
    unsigned int u = __float_as_uint(f);
    unsigned int r = (u + 0x7FFFu + ((u >> 16) & 1u)) >> 16;   // round-nearest-even
    return (unsigned short)r;
}
static __device__ __forceinline__ float bf2f(unsigned short h) {
    return __uint_as_float(((unsigned int)h) << 16);
}

// ---------------------------------------------------------------------------
// Kernel 1: ftb = bf16(feat @ W^T), fused el/er epilogue + fused dst-histogram.
// The histogram (850K atomics into L2-resident deg[]) only depends on input
// dst, so it rides along at kernel start and overlaps the GEMM body.
// Tile 64 rows x 128 cols; LDS 48KB -> 3 blocks/CU; all LDS reads b128.
// ---------------------------------------------------------------------------
#define GM 64
__global__ __launch_bounds__(256) void gemm_ft(const float* __restrict__ feat,
                                               const float* __restrict__ W,
                                               const float* __restrict__ attn_l,
                                               const float* __restrict__ attn_r,
                                               const int* __restrict__ dst,
                                               int* __restrict__ deg, int E,
                                               unsigned short* __restrict__ ftb,
                                               float* __restrict__ el,
                                               float* __restrict__ er, int N) {
    // ---- fused histogram (deg pre-zeroed by the memset before this kernel) ----
    {
        const int gstride = gridDim.x * 256;
        for (int i = blockIdx.x * 256 + threadIdx.x; i < E; i += gstride)
            atomicAdd(&deg[dst[i]], 1);
    }

    __shared__ float Wt[64][128];   // Wt[kk][c] = W[c][kh*64+kk]
    __shared__ float Fl[64][64];    // Fl[r][kk]  = feat[rbase+r][kh*64+kk]

    const int tid = threadIdx.x;
    const int m   = tid & 31;       // col group: c0 = 4*m
    const int rg  = tid >> 5;       // row group: r0 = 8*rg
    const int c0  = m * 4;
    const int r0  = rg * 8;
    const int rbase = blockIdx.x * GM;

    float4 acc4[8];
#pragma unroll
    for (int r = 0; r < 8; ++r) acc4[r] = make_float4(0.f, 0.f, 0.f, 0.f);

    const float4* W4 = (const float4*)W;
    const float4* F4 = (const float4*)feat;

    for (int kh = 0; kh < 2; ++kh) {
        __syncthreads();
        for (int i = tid; i < 2048; i += 256) {
            int c = i & 127, q2 = i >> 7;
            float4 w = W4[c * 32 + kh * 16 + q2];
            Wt[q2 * 4 + 0][c] = w.x;
            Wt[q2 * 4 + 1][c] = w.y;
            Wt[q2 * 4 + 2][c] = w.z;
            Wt[q2 * 4 + 3][c] = w.w;
        }
        for (int i = tid; i < 1024; i += 256) {
            int r = i >> 4, q = i & 15;
            int gr = rbase + r;
            float4 v = (gr < N) ? F4[(size_t)gr * 32 + kh * 16 + q]
                                : make_float4(0.f, 0.f, 0.f, 0.f);
            *(float4*)&Fl[r][q * 4] = v;
        }
        __syncthreads();

        for (int kk = 0; kk < 64; kk += 4) {
            float4 w0 = *(const float4*)&Wt[kk + 0][c0];
            float4 w1 = *(const float4*)&Wt[kk + 1][c0];
            float4 w2 = *(const float4*)&Wt[kk + 2][c0];
            float4 w3 = *(const float4*)&Wt[kk + 3][c0];
#pragma unroll
            for (int r = 0; r < 8; ++r) {
                float4 f = *(const float4*)&Fl[r0 + r][kk];
                float4 a = acc4[r];
                a.x += f.x * w0.x + f.y * w1.x + f.z * w2.x + f.w * w3.x;
                a.y += f.x * w0.y + f.y * w1.y + f.z * w2.y + f.w * w3.y;
                a.z += f.x * w0.z + f.y * w1.z + f.z * w2.z + f.w * w3.z;
                a.w += f.x * w0.w + f.y * w1.w + f.z * w2.w + f.w * w3.w;
                acc4[r] = a;
            }
        }
    }

    // --- stores: bf16 ftb ---
#pragma unroll
    for (int r = 0; r < 8; ++r) {
        int gr = rbase + r0 + r;
        if (gr < N) {
            ushort4 o;
            o.x = f2bf(acc4[r].x); o.y = f2bf(acc4[r].y);
            o.z = f2bf(acc4[r].z); o.w = f2bf(acc4[r].w);
            *(ushort4*)&ftb[(size_t)gr * HD + c0] = o;
        }
    }

    // --- fused el/er ---
    const float4 al = *(const float4*)(attn_l + c0);
    const float4 ar = *(const float4*)(attn_r + c0);
    const int head = m >> 3;
#pragma unroll
    for (int r = 0; r < 8; ++r) {
        float4 a = acc4[r];
        float vl = a.x * al.x + a.y * al.y + a.z * al.z + a.w * al.w;
        float vr = a.x * ar.x + a.y * ar.y + a.z * ar.z + a.w * ar.w;
        vl += __shfl_xor(vl, 1); vr += __shfl_xor(vr, 1);
        vl += __shfl_xor(vl, 2); vr += __shfl_xor(vr, 2);
        vl += __shfl_xor(vl, 4); vr += __shfl_xor(vr, 4);
        if ((m & 7) == 0) {
            int gr = rbase + r0 + r;
            if (gr < N) {
                el[gr * 4 + head] = vl;
                er[gr * 4 + head] = vr;
            }
        }
    }
}

// ---------------------------------------------------------------------------
// Single-kernel exclusive scan: block b redundantly sums deg[0 .. 256b)
// (coalesced, deg is L2-resident: <=19MB aggregate re-reads across 196
// blocks), then intra-block shuffle scan. No atomics, no inter-block comms.
// ---------------------------------------------------------------------------
__global__ __launch_bounds__(256) void scan_onepass(const int* __restrict__ deg,
                                                    int* __restrict__ row_start,
                                                    int* __restrict__ cursor,
                                                    int N, int E) {
    const int b = blockIdx.x, tid = threadIdx.x;
    const int begin = b * 256;
    const int lane = tid & 63, wid = tid >> 6;

    // 1) base = sum of deg[0..begin)
    int part = 0;
    for (int j = tid; j < begin; j += 256) part += deg[j];
    int r = part;
#pragma unroll
    for (int off = 32; off > 0; off >>= 1) r += __shfl_down(r, off);
    __shared__ int wsum[4];
    __shared__ int wscn[4];
    if (lane == 0) wsum[wid] = r;
    __syncthreads();
    const int base = wsum[0] + wsum[1] + wsum[2] + wsum[3];

    // 2) intra-block inclusive scan of this block's 256 degrees
    const int i = begin + tid;
    const int v = (i < N) ? deg[i] : 0;
    int x = v;
#pragma unroll
    for (int off = 1; off < 64; off <<= 1) {
        int y = __shfl_up(x, off);
        if (lane >= off) x += y;
    }
    if (lane == 63) wscn[wid] = x;
    __syncthreads();
    int add = base;
    for (int w = 0; w < wid; ++w) add += wscn[w];
    const int excl = add + x - v;
    if (i < N) { row_start[i] = excl; cursor[i] = excl; }
    if (b == 0 && tid == 0) row_start[N] = E;
}

__global__ void scatter_kernel(const int* __restrict__ src, const int* __restrict__ dst,
                               int* __restrict__ cursor, int* __restrict__ sorted_src,
                               int E) {
    int i = blockIdx.x * blockDim.x + threadIdx.x;
    if (i < E) {
        int pos = atomicAdd(&cursor[dst[i]], 1);
        sorted_src[pos] = src[i];
    }
}

// ---------------------------------------------------------------------------
// Aggregation: one 64-lane wave per destination node.
// Lane owns channels c0=2*lane, c0+1 (same head -> one exp/edge).
// ft gathered as bf16 (ushort2 = 4B/lane = 256B/edge/wave).
// No max pass (e bounded, softmax identical without max-shift).
// ---------------------------------------------------------------------------
__global__ __launch_bounds__(256) void aggregate_kernel(
        const unsigned short* __restrict__ ftb, const float* __restrict__ el,
        const float* __restrict__ er, const int* __restrict__ row_start,
        const int* __restrict__ sorted_src, const float* __restrict__ bias,
        float* __restrict__ out, int N) {
    const int n    = (blockIdx.x * blockDim.x + threadIdx.x) >> 6;
    const int lane = threadIdx.x & 63;
    if (n >= N) return;
    const int h  = lane >> 4;
    const int c0 = lane * 2;

    const float ern = er[(n << 2) + h];
    ushort2 tn = *(const ushort2*)(ftb + (size_t)n * HD + c0);
    const float ftn0 = bf2f(tn.x), ftn1 = bf2f(tn.y);

    const int s0 = row_start[n], s1 = row_start[n + 1];

    float a0 = 0.f, a1 = 0.f;   // sum exp * ft[src]
    float b0 = 0.f, b1 = 0.f;   // sum ft[src]
    float sum = 0.f;            // sum exp

    int i = s0;
    for (; i + 2 <= s1; i += 2) {
        int sA = sorted_src[i], sB = sorted_src[i + 1];
        float   eA = el[(sA << 2) + h];
        float   eB = el[(sB << 2) + h];
        ushort2 rA = *(const ushort2*)(ftb + (size_t)sA * HD + c0);
        ushort2 rB = *(const ushort2*)(ftb + (size_t)sB * HD + c0);
        eA += ern; eB += ern;
        eA = eA > 0.f ? eA : NEG_SLOPE * eA;
        eB = eB > 0.f ? eB : NEG_SLOPE * eB;
        float xA = __expf(eA), xB = __expf(eB);
        float fAx = bf2f(rA.x), fAy = bf2f(rA.y);
        float fBx = bf2f(rB.x), fBy = bf2f(rB.y);
        sum += xA + xB;
        a0 += xA * fAx + xB * fBx;
        a1 += xA * fAy + xB * fBy;
        b0 += fAx + fBx;
        b1 += fAy + fBy;
    }
    if (i < s1) {
        int s = sorted_src[i];
        float e = el[(s << 2) + h] + ern;
        e = e > 0.f ? e : NEG_SLOPE * e;
        float x = __expf(e);
        ushort2 rr = *(const ushort2*)(ftb + (size_t)s * HD + c0);
        float fx = bf2f(rr.x), fy = bf2f(rr.y);
        sum += x;
        a0 += x * fx; a1 += x * fy;
        b0 += fx;     b1 += fy;
    }

    float inv = 1.f / sum;
    float2 o;
    o.x = a0 * inv + ftn0 * b0 + bias[c0];
    o.y = a1 * inv + ftn1 * b1 + bias[c0 + 1];
    *(float2*)(out + (size_t)n * HD + c0) = o;
}

// ---------------------------------------------------------------------------
extern "C" void kernel_launch(void* const* d_in, const int* in_sizes, int n_in,
                              void* d_out, int out_size, void* d_ws, size_t ws_size,
                              hipStream_t stream) {
    const float* feat   = (const float*)d_in[0];
    const int*   src    = (const int*)d_in[1];
    const int*   dst    = (const int*)d_in[2];
    const float* W      = (const float*)d_in[3];
    const float* attn_l = (const float*)d_in[4];
    const float* attn_r = (const float*)d_in[5];
    const float* bias   = (const float*)d_in[6];

    const int N = in_sizes[0] / IN_FEATS;
    const int E = in_sizes[1];

    char* p = (char*)d_ws;
    auto alloc = [&](size_t bytes) {
        char* q = p;
        p += (bytes + 255) & ~(size_t)255;
        return q;
    };
    unsigned short* ftb = (unsigned short*)alloc((size_t)N * HD * 2);
    float* el         = (float*)alloc((size_t)N * 4 * 4);
    float* er         = (float*)alloc((size_t)N * 4 * 4);
    int*   deg        = (int*)alloc((size_t)N * 4);
    int*   row_start  = (int*)alloc((size_t)(N + 1) * 4);
    int*   cursor     = (int*)alloc((size_t)N * 4);
    int*   sorted_src = (int*)alloc((size_t)E * 4);

    // 1) zero deg (hist rides inside gemm, which is stream-ordered after this)
    hipMemsetAsync(deg, 0, (size_t)N * 4, stream);

    // 2) projection + fused el/er + fused histogram
    gemm_ft<<<(N + GM - 1) / GM, 256, 0, stream>>>(feat, W, attn_l, attn_r,
                                                   dst, deg, E, ftb, el, er, N);

    // 3) scan (one kernel)
    const int nb = (N + 255) / 256;
    scan_onepass<<<nb, 256, 0, stream>>>(deg, row_start, cursor, N, E);

    // 4) scatter into CSR
    scatter_kernel<<<(E + 255) / 256, 256, 0, stream>>>(src, dst, cursor, sorted_src, E);

    // 5) aggregation: one wave per node
    long long threads = (long long)N * 64;
    int agg_blocks = (int)((threads + 255) / 256);
    aggregate_kernel<<<agg_blocks, 256, 0, stream>>>(ftb, el, er, row_start, sorted_src,
                                                     bias, (float*)d_out, N);
}